// Round 9
// baseline (195.768 us; speedup 1.0000x reference)
//
#include <hip/hip_runtime.h>

// ZeroPad2d: in [32,2048,2048] f32 -> out [32,2050,2050] f32, pad=1.
// R9 = R8 (pure-dword streaming, the best structure: 189 us) + NONTEMPORAL
// LOADS only. Input is touch-once; NT (no-allocate) loads keep the 537 MB
// read stream from churning the 32 MB L2, leaving it free to merge/combine
// the write stream (incl. row-edge partial lines). Stores stay NORMAL
// (R3 showed NT stores regress: no-allocate partial-sector writes RMW).
//   - grid (2050, 32): one 256-thread block per OUTPUT row; no divisions
//   - interior row: 8 independent NT dword loads, 8 normal dword stores;
//     each instruction is lane-contiguous (thread->slice mapping)
//   - pad rows (y=0, y=2049): 8 dword zero-stores
//   - lanes 0/1 write the row's left/right pad zeros
// Every output element is written on every call (harness does not re-poison).

#define H 2048
#define W 2048
#define HPAD 2050
#define WPAD 2050

__global__ __launch_bounds__(256) void zeropad_dw(const float* __restrict__ in,
                                                  float* __restrict__ out) {
    const unsigned y = blockIdx.x;     // 0..2049 (padded row)
    const unsigned c = blockIdx.y;     // 0..31   (channel)
    const unsigned t = threadIdx.x;    // 0..255
    float* orow = out + ((size_t)c * HPAD + y) * WPAD;

    if (y >= 1u && y <= (unsigned)H) {
        // interior row: out[y][1..2048] = in[y-1][0..2047]
        const float* srow = in + ((size_t)c * H + (y - 1u)) * W;
        float v[8];
        #pragma unroll
        for (int j = 0; j < 8; ++j)            // 8 independent NT coalesced loads
            v[j] = __builtin_nontemporal_load(srow + t + 256u * j);
        #pragma unroll
        for (int j = 0; j < 8; ++j)            // 8 normal coalesced dword stores
            orow[1u + t + 256u * j] = v[j];
        if (t < 2u) orow[t ? (WPAD - 1u) : 0u] = 0.f;   // left/right pad
    } else {
        // top/bottom pad row: 2050 zeros
        #pragma unroll
        for (int j = 0; j < 8; ++j)
            orow[t + 256u * j] = 0.f;          // covers 0..2047
        if (t < 2u) orow[2048u + t] = 0.f;     // covers 2048..2049
    }
}

extern "C" void kernel_launch(void* const* d_in, const int* in_sizes, int n_in,
                              void* d_out, int out_size, void* d_ws, size_t ws_size,
                              hipStream_t stream) {
    const float* in = (const float*)d_in[0];
    float* out = (float*)d_out;
    dim3 grid(HPAD, 32);                       // 2050 rows x 32 channels
    zeropad_dw<<<grid, 256, 0, stream>>>(in, out);
}